// Round 16
// baseline (273.992 us; speedup 1.0000x reference)
//
#include <hip/hip_runtime.h>

#define NT   198     // n_time
#define BB   32      // batch
#define CC   16      // emg channels
#define TT   8000    // emg time
#define FF   512     // conv filters
#define KW   65      // conv kernel width
#define HD   512     // hidden
#define OUT  20
#define CJ   (CC*KW) // 1040
#define KP   1056    // K padded to 33*32
#define MM   (NT*BB) // 6336
#define TOUT 7936    // T - 64
#define NPS  50      // num_pos_steps

typedef float f4 __attribute__((ext_vector_type(4)));

// workspace layout (floats); base total = 10,623,232 floats = 42.5 MB
#define WS_CW 0                       // KP*HD = 540672
#define WS_BX (WS_CW + KP*HD)         // 540672
#define WS_X  (WS_BX + HD)            // 541184
#define WS_PR (WS_X  + MM*HD)         // 3785216
#define WS_ET (WS_PR + MM*OUT)        // 3911936
#define WS_W2T (WS_ET + KP*MM)        // 10602752
#define WS_X4 (WS_W2T + 2*OUT*HD)     // 10623232  (optional, big-ws path)
#define WS_X5 (WS_X4 + MM*HD)         // 13867264
#define WS_NEED_BIG ((size_t)(WS_X5 + MM*HD) * 4)   // 68.4 MB

// ---- k_pre: fused {Et interp+zero-pad | CW GEMM | bX + w2t} by block range ----
#define ESPAN 2688
#define NB_E  (3 * (BB * CC + 4))     // 1548
#define NB_CW (((KP + 63) / 64) * (HD / 64))  // 17*8 = 136
__global__ __launch_bounds__(256) void k_pre(const float* __restrict__ emg,
                                             const float* __restrict__ cwraw,
                                             const float* __restrict__ w1,
                                             const float* __restrict__ conv_b,
                                             const float* __restrict__ b1,
                                             const float* __restrict__ w2,
                                             float* __restrict__ Et,
                                             float* __restrict__ CW,
                                             float* __restrict__ bX,
                                             float* __restrict__ w2t) {
    __shared__ float sh[2 * 32 * 68];  // 4352 floats; aliased per role
    const int bid = blockIdx.x;
    const int tid = threadIdx.x;

    if (bid < NB_E) {
        // ---------- Et role ----------
        const int bx = bid % (BB * CC + 4);
        const int tc = bid / (BB * CC + 4);      // 0..2
        if (bx >= BB * CC) {                     // zero-pad rows CJ..KP-1
            int idx = (bx - BB * CC) * 3 + tc;   // 0..11
            f4* zp = (f4*)(Et + (size_t)CJ * MM);
            f4 z = {0.f, 0.f, 0.f, 0.f};
            for (int j = tid; j < 2112; j += 256) zp[(size_t)idx * 2112 + j] = z;
            return;
        }
        float* lds_e = sh;
        const int bq = bx >> 4, c = bx & 15;
        const int t0 = tc * 66;
        const float CSTEP = 7935.0f / 197.0f;
        const int elo0 = (int)floorf((float)t0 * CSTEP);
        const float* erow = emg + (size_t)(bq * CC + c) * TT;
        for (int i = tid; i < ESPAN; i += 256) {
            int g = elo0 + i;
            lds_e[i] = erow[(g < TT) ? g : (TT - 1)];
        }
        __syncthreads();
        for (int o = tid; o < 65 * 66; o += 256) {
            int j = o / 66;
            int tl = o - j * 66;
            int t = t0 + tl;
            float src = (float)t * CSTEP;
            float fl = floorf(src);
            int lo = (int)fl;
            float w = src - fl;
            int dhi = (w > 0.f && lo < TOUT - 1) ? 1 : 0;
            int li = lo - elo0 + j;
            float v = (1.0f - w) * lds_e[li] + w * lds_e[li + dhi];
            Et[(size_t)(c * KW + j) * MM + bq * NT + t] = v;
        }
    } else if (bid < NB_E + NB_CW) {
        // ---------- CW role: CW[cj][h] = sum_f conv_w[f][cj]*w1[f][h] ----------
        const int cb = bid - NB_E;
        const int m0 = (cb % 17) * 64;           // cj
        const int n0 = (cb / 17) * 64;           // h
        float (*As)[68] = (float(*)[68])sh;
        float (*Bs)[68] = (float(*)[68])(sh + 32 * 68);
        const int tx = tid & 15, ty = tid >> 4;
        const int am = tid & 63;
        const int kb8 = (tid >> 6) * 8;
        const int mrow = m0 + am;
        const int mclamp = mrow < CJ ? mrow : CJ - 1;

        f4 acc[4] = {};
        for (int k0 = 0; k0 < FF; k0 += 32) {
            __syncthreads();
            #pragma unroll
            for (int s = 0; s < 8; ++s)
                As[kb8 + s][am] = cwraw[(size_t)(k0 + kb8 + s) * CJ + mclamp];
            {
                int kb = tid >> 4, c4 = tid & 15;
                *(f4*)&Bs[kb][c4 * 4]      = *(const f4*)(w1 + (size_t)(k0 + kb) * HD + n0 + c4 * 4);
                *(f4*)&Bs[kb + 16][c4 * 4] = *(const f4*)(w1 + (size_t)(k0 + kb + 16) * HD + n0 + c4 * 4);
            }
            __syncthreads();
            #pragma unroll
            for (int kk = 0; kk < 32; ++kk) {
                f4 a = *(f4*)&As[kk][ty * 4];
                f4 bq = *(f4*)&Bs[kk][tx * 4];
                acc[0] += a[0] * bq; acc[1] += a[1] * bq;
                acc[2] += a[2] * bq; acc[3] += a[3] * bq;
            }
        }
        #pragma unroll
        for (int i = 0; i < 4; ++i) {
            int r = m0 + ty * 4 + i;
            if (r < CJ) {
                *(f4*)(CW + (size_t)r * HD + n0 + tx * 4) = acc[i];
            } else if (r < KP) {
                f4 z = {0.f, 0.f, 0.f, 0.f};
                *(f4*)(CW + (size_t)r * HD + n0 + tx * 4) = z;
            }
        }
    } else {
        // ---------- small role: bX (2 blocks) + w2t (40 blocks) ----------
        const int sb = bid - NB_E - NB_CW;       // 0..41
        if (sb < 2) {
            int h = sb * 256 + tid;
            float acc = b1[h];
            for (int f = 0; f < FF; ++f) acc += conv_b[f] * w1[f * HD + h];
            bX[h] = acc;
        } else {
            int q = sb - 2;                      // 0..39
            w2t[(size_t)q * HD + tid]       = w2[(size_t)tid * (2 * OUT) + q];
            w2t[(size_t)q * HD + 256 + tid] = w2[(size_t)(256 + tid) * (2 * OUT) + q];
        }
    }
}

// ---- k_x96: X = Et^T @ CW (+bX), tile 96x256, 192 thr (3 waves), 8x16 micro,
//      K-split 6 (NK={6,6,6,5,5,5}), single-buffer LDS. 9.3 waves/CU. ----
__global__ __launch_bounds__(192) void k_x96(const float* __restrict__ Et,
                                             const float* __restrict__ CW,
                                             const float* __restrict__ bX,
                                             float* __restrict__ X0,
                                             float* __restrict__ X1,
                                             float* __restrict__ X2,
                                             float* __restrict__ X3,
                                             float* __restrict__ X4,
                                             float* __restrict__ X5) {
    __shared__ float As[32][100];        // 96 + pad 4 (stride ≡ 4 mod 32)
    __shared__ float Bs[4][32][68];      // byte-identical pattern to R15 (0-conflict)
    const int m0 = blockIdx.x * 96;
    const int n0 = blockIdx.y * 256;
    const int kc = blockIdx.z;
    const int kbase = (kc < 3) ? kc * 192 : 576 + (kc - 3) * 160;
    const int NK = (kc < 3) ? 6 : 5;     // rows >= CJ are zero-padded
    const int tid = threadIdx.x;
    const int tm = tid >> 4;             // 0..11 : rows 8tm..8tm+7
    const int tn = tid & 15;             // 0..15 : cols 4tn + 64e (e=0..3)

    f4 acc[4][8] = {};                   // [e][row]

    for (int kt = 0; kt < NK; ++kt) {
        const int k0 = kbase + kt * 32;
        __syncthreads();
        // A: 32 rows x 24 f4 = 768 f4 over 192 threads (4 each)
        #pragma unroll
        for (int s = 0; s < 4; ++s) {
            int i = tid + s * 192;
            int row = i / 24, cf = i - row * 24;
            *(f4*)&As[row][cf * 4] =
                *(const f4*)(Et + (size_t)(k0 + row) * MM + m0 + cf * 4);
        }
        // B: 32 rows x 64 f4 = 2048 f4 over 192 threads (10-11 each)
        #pragma unroll
        for (int s = 0; s < 11; ++s) {
            int i = tid + s * 192;
            if (i < 2048) {
                int row = i >> 6, cf = i & 63;
                f4 v = *(const f4*)(CW + (size_t)(k0 + row) * HD + n0 + cf * 4);
                *(f4*)&Bs[cf >> 4][row][(cf & 15) * 4] = v;
            }
        }
        __syncthreads();
        #pragma unroll
        for (int kk = 0; kk < 32; ++kk) {
            f4 a0 = *(const f4*)&As[kk][tm * 8];
            f4 a1 = *(const f4*)&As[kk][tm * 8 + 4];
            f4 b0 = *(const f4*)&Bs[0][kk][tn * 4];
            f4 b1 = *(const f4*)&Bs[1][kk][tn * 4];
            f4 b2q = *(const f4*)&Bs[2][kk][tn * 4];
            f4 b3 = *(const f4*)&Bs[3][kk][tn * 4];
            #pragma unroll
            for (int i = 0; i < 4; ++i) {
                acc[0][i] += a0[i] * b0;  acc[1][i] += a0[i] * b1;
                acc[2][i] += a0[i] * b2q; acc[3][i] += a0[i] * b3;
                acc[0][i + 4] += a1[i] * b0;  acc[1][i + 4] += a1[i] * b1;
                acc[2][i + 4] += a1[i] * b2q; acc[3][i + 4] += a1[i] * b3;
            }
        }
    }

    float* Xo = (kc == 0) ? X0 : (kc == 1) ? X1 : (kc == 2) ? X2 :
                (kc == 3) ? X3 : (kc == 4) ? X4 : X5;
    if (kc == 0) {
        #pragma unroll
        for (int e = 0; e < 4; ++e) {
            f4 bx = *(const f4*)(bX + n0 + e * 64 + tn * 4);
            #pragma unroll
            for (int i = 0; i < 8; ++i) {
                size_t off = (size_t)(m0 + 8 * tm + i) * HD + n0 + e * 64 + tn * 4;
                *(f4*)(Xo + off) = acc[e][i] + bx;
            }
        }
    } else {
        #pragma unroll
        for (int e = 0; e < 4; ++e)
            #pragma unroll
            for (int i = 0; i < 8; ++i) {
                size_t off = (size_t)(m0 + 8 * tm + i) * HD + n0 + e * 64 + tn * 4;
                *(f4*)(Xo + off) = acc[e][i];
            }
    }
}

// ---- k_x12 (R15 fallback): tile 64x256, 128 thr, 8x16 micro, K-split 4 ----
__global__ __launch_bounds__(128) void k_x12(const float* __restrict__ Et,
                                             const float* __restrict__ CW,
                                             const float* __restrict__ bX,
                                             float* __restrict__ X0,
                                             float* __restrict__ X1,
                                             float* __restrict__ X2,
                                             float* __restrict__ X3) {
    __shared__ float As[32][68];
    __shared__ float Bs[4][32][68];
    const int m0 = blockIdx.x * 64;
    const int n0 = blockIdx.y * 256;
    const int kc = blockIdx.z;
    const int kbase = kc * 256;
    const int NK = (kc == 3) ? 9 : 8;
    const int tid = threadIdx.x;
    const int tm = tid >> 4;
    const int tn = tid & 15;
    const int akr = tid >> 4;
    const int ag  = tid & 15;
    const int bkr = tid >> 6;
    const int bg  = tid & 63;
    const int be  = bg >> 4;
    const int bc  = (bg & 15) * 4;

    f4 acc[4][8] = {};

    for (int kt = 0; kt < NK; ++kt) {
        const int k0 = kbase + kt * 32;
        __syncthreads();
        #pragma unroll
        for (int s = 0; s < 4; ++s) {
            f4 v = *(const f4*)(Et + (size_t)(k0 + akr + 8 * s) * MM + m0 + ag * 4);
            *(f4*)&As[akr + 8 * s][ag * 4] = v;
        }
        #pragma unroll
        for (int s = 0; s < 16; ++s) {
            int kr = bkr + 2 * s;
            f4 v = *(const f4*)(CW + (size_t)(k0 + kr) * HD + n0 + bg * 4);
            *(f4*)&Bs[be][kr][bc] = v;
        }
        __syncthreads();
        #pragma unroll
        for (int kk = 0; kk < 32; ++kk) {
            f4 a0 = *(const f4*)&As[kk][tm * 8];
            f4 a1 = *(const f4*)&As[kk][tm * 8 + 4];
            f4 b0 = *(const f4*)&Bs[0][kk][tn * 4];
            f4 b1 = *(const f4*)&Bs[1][kk][tn * 4];
            f4 b2q = *(const f4*)&Bs[2][kk][tn * 4];
            f4 b3 = *(const f4*)&Bs[3][kk][tn * 4];
            #pragma unroll
            for (int i = 0; i < 4; ++i) {
                acc[0][i] += a0[i] * b0;  acc[1][i] += a0[i] * b1;
                acc[2][i] += a0[i] * b2q; acc[3][i] += a0[i] * b3;
                acc[0][i + 4] += a1[i] * b0;  acc[1][i + 4] += a1[i] * b1;
                acc[2][i + 4] += a1[i] * b2q; acc[3][i + 4] += a1[i] * b3;
            }
        }
    }

    float* Xo = (kc == 0) ? X0 : (kc == 1) ? X1 : (kc == 2) ? X2 : X3;
    if (kc == 0) {
        #pragma unroll
        for (int e = 0; e < 4; ++e) {
            f4 bx = *(const f4*)(bX + n0 + e * 64 + tn * 4);
            #pragma unroll
            for (int i = 0; i < 8; ++i) {
                size_t off = (size_t)(m0 + 8 * tm + i) * HD + n0 + e * 64 + tn * 4;
                *(f4*)(Xo + off) = acc[e][i] + bx;
            }
        }
    } else {
        #pragma unroll
        for (int e = 0; e < 4; ++e)
            #pragma unroll
            for (int i = 0; i < 8; ++i) {
                size_t off = (size_t)(m0 + 8 * tm + i) * HD + n0 + e * 64 + tn * 4;
                *(f4*)(Xo + off) = acc[e][i];
            }
    }
}

// ---- k_sum4 / k_sum6: X0 += partials ----
__global__ __launch_bounds__(256) void k_sum4(float* __restrict__ X0,
                                              const float* __restrict__ X1,
                                              const float* __restrict__ X2,
                                              const float* __restrict__ X3) {
    size_t i = (size_t)blockIdx.x * 256 + threadIdx.x;
    f4 a = ((const f4*)X0)[i];
    f4 b = ((const f4*)X1)[i];
    f4 c = ((const f4*)X2)[i];
    f4 d = ((const f4*)X3)[i];
    ((f4*)X0)[i] = (a + b) + (c + d);
}

__global__ __launch_bounds__(256) void k_sum6(float* __restrict__ X0,
                                              const float* __restrict__ X1,
                                              const float* __restrict__ X2,
                                              const float* __restrict__ X3,
                                              const float* __restrict__ X4,
                                              const float* __restrict__ X5) {
    size_t i = (size_t)blockIdx.x * 256 + threadIdx.x;
    f4 a = ((const f4*)X0)[i];
    f4 b = ((const f4*)X1)[i];
    f4 c = ((const f4*)X2)[i];
    f4 d = ((const f4*)X3)[i];
    f4 e = ((const f4*)X4)[i];
    f4 f = ((const f4*)X5)[i];
    ((f4*)X0)[i] = ((a + b) + (c + d)) + (e + f);
}

// ---- scan (blocks 0..31) + ja/mask copies (blocks 32..703) ----
#define DPPADD(x, ctrl) ((x) + __int_as_float(__builtin_amdgcn_mov_dpp(__float_as_int(x), (ctrl), 0xf, 0xf, true)))

#define SCAN_STEP(T, ISPOS) { \
    if (aown) { \
        int tp = (T) + 2; if (tp > NT - 1) tp = NT - 1; \
        float2 xf = *(const float2*)(Xr + (size_t)tp * HD); \
        f4 pp[5]; \
        _Pragma("unroll") \
        for (int g = 0; g < 5; ++g) pp[g] = *(const f4*)&prev_lds[(T) & 1][g * 4]; \
        float h0a = xc.x, h0b = 0.f, h1a = xc.y, h1b = 0.f; \
        _Pragma("unroll") \
        for (int j = 0; j < 10; ++j) { \
            float pj = pp[j >> 2][j & 3]; \
            h0a = fmaf(pj, w1p[j].x, h0a); h1a = fmaf(pj, w1p[j].y, h1a); } \
        _Pragma("unroll") \
        for (int j = 10; j < OUT; ++j) { \
            float pj = pp[j >> 2][j & 3]; \
            h0b = fmaf(pj, w1p[j].x, h0b); h1b = fmaf(pj, w1p[j].y, h1b); } \
        float h0 = fmaxf(h0a + h0b, 0.f), h1 = fmaxf(h1a + h1b, 0.f); \
        float2 hw; hw.x = h0; hw.y = h1; \
        *(float2*)&h_lds[(T) & 1][tid >> 4][(2 * tid) & 31] = hw; \
        xc = xn; xn = xf; \
    } \
    __syncthreads(); \
    f4 alo = {0.f, 0.f, 0.f, 0.f}, ahi = {0.f, 0.f, 0.f, 0.f}; \
    _Pragma("unroll") \
    for (int s = 0; s < 4; ++s) { \
        f4 hv0 = *(const f4*)&h_lds[(T) & 1][r][s * 4]; \
        f4 hv1 = *(const f4*)&h_lds[(T) & 1][r][(s + 4) * 4]; \
        alo += hv0 * ((ISPOS) ? wqp[s] : wqv[s]); \
        ahi += hv1 * ((ISPOS) ? wqp[s + 4] : wqv[s + 4]); } \
    f4 a = alo + ahi; \
    float sum = (a[0] + a[1]) + (a[2] + a[3]); \
    sum = DPPADD(sum, 0xB1);   /* xor1  */ \
    sum = DPPADD(sum, 0x4E);   /* xor2  */ \
    sum = DPPADD(sum, 0x141);  /* row_half_mirror */ \
    sum = DPPADD(sum, 0x140);  /* row_mirror */ \
    float outv = sum + ((ISPOS) ? b2p : b2v); \
    myq = (ISPOS) ? outv : (myq + outv); \
    if (r == 0) { \
        predrow[(size_t)(T) * OUT + q] = myq; \
        prev_lds[((T) + 1) & 1][q] = myq; } \
    __syncthreads(); }

__global__ __launch_bounds__(320, 1) void k_scan(
        const float* __restrict__ X, const float* __restrict__ w1,
        const float* __restrict__ w2t, const float* __restrict__ b2,
        const float* __restrict__ jang, const int* __restrict__ provide,
        float* __restrict__ preds, const unsigned char* __restrict__ m,
        float* __restrict__ outp) {
    const int bid = blockIdx.x;
    const int tid = threadIdx.x;
    const int NF4 = TOUT / 4;    // 1984

    if (bid >= BB) {
        // ---- copy role: ja rows (cb<640) and mask rows (cb>=640) ----
        int cb = bid - BB;
        if (cb < BB * OUT) {
            f4* op = (f4*)(outp + (size_t)BB * OUT * TOUT + (size_t)cb * TOUT);
            const f4* ip = (const f4*)(jang + (size_t)cb * TT + 32);
            for (int i = tid; i < NF4; i += 320) op[i] = ip[i];
        } else {
            int b = cb - BB * OUT;
            f4* op = (f4*)(outp + (size_t)2 * BB * OUT * TOUT + (size_t)b * TOUT);
            const uchar4* mp = (const uchar4*)(m + (size_t)b * TT + 32);
            for (int i = tid; i < NF4; i += 320) {
                uchar4 mv = mp[i];
                f4 o;
                o[0] = mv.x ? 1.0f : 0.0f; o[1] = mv.y ? 1.0f : 0.0f;
                o[2] = mv.z ? 1.0f : 0.0f; o[3] = mv.w ? 1.0f : 0.0f;
                op[i] = o;
            }
        }
        return;
    }

    __shared__ float h_lds[2][16][36];
    __shared__ __align__(16) float prev_lds[2][20];
    const int b = bid;
    const int q = tid >> 4;        // 0..19
    const int r = tid & 15;        // 0..15
    const bool aown = tid < 256;

    float2 w1p[OUT];
    if (aown) {
        #pragma unroll
        for (int j = 0; j < OUT; ++j)
            w1p[j] = *(const float2*)(w1 + (size_t)(FF + j) * HD + 2 * tid);
    }
    f4 wqp[8], wqv[8];
    #pragma unroll
    for (int s = 0; s < 8; ++s) {
        wqp[s] = *(const f4*)(w2t + (size_t)q * HD + r * 32 + s * 4);
        wqv[s] = *(const f4*)(w2t + (size_t)(OUT + q) * HD + r * 32 + s * 4);
    }
    float b2p = b2[q], b2v = b2[OUT + q];

    float pvf = provide[0] ? 1.0f : 0.0f;
    float myq = pvf * jang[(size_t)(b * OUT + q) * TT + 32];
    if (r == 0) prev_lds[0][q] = myq;

    const float* Xr = X + (size_t)b * NT * HD + 2 * tid;
    float* predrow = preds + (size_t)b * NT * OUT;
    float2 xc = {0.f, 0.f}, xn = {0.f, 0.f};
    if (aown) {
        xc = *(const float2*)(Xr);
        xn = *(const float2*)(Xr + HD);
    }
    __syncthreads();

    for (int t = 0; t < NPS; ++t) { SCAN_STEP(t, true) }
    for (int t = NPS; t < NT; ++t) { SCAN_STEP(t, false) }
}

// ---- k_up: pred_up only (640 blocks), f4-vectorized ----
__global__ __launch_bounds__(256) void k_up(const float* __restrict__ preds,
                                            float* __restrict__ outp) {
    __shared__ float row[NT];
    const int rc = blockIdx.x;
    const int tid = threadIdx.x;
    const int NF4 = TOUT / 4;     // 1984
    int bq = rc / OUT, ch = rc - bq * OUT;
    if (tid < NT) row[tid] = preds[(size_t)(bq * NT + tid) * OUT + ch];
    __syncthreads();
    const float scale = (float)NT / (float)TOUT;
    f4* op = (f4*)(outp + (size_t)rc * TOUT);
    for (int i = tid; i < NF4; i += 256) {
        f4 o;
        #pragma unroll
        for (int e = 0; e < 4; ++e) {
            int idx = 4 * i + e;
            float src = ((float)idx + 0.5f) * scale - 0.5f;
            src = fminf(fmaxf(src, 0.0f), (float)(NT - 1));
            float fl = floorf(src);
            int lo = (int)fl;
            int hi = lo + 1; if (hi > NT - 1) hi = NT - 1;
            float w = src - fl;
            o[e] = row[lo] * (1.0f - w) + row[hi] * w;
        }
        op[i] = o;
    }
}

extern "C" void kernel_launch(void* const* d_in, const int* in_sizes, int n_in,
                              void* d_out, int out_size, void* d_ws, size_t ws_size,
                              hipStream_t stream) {
    const float* emg     = (const float*)d_in[0];
    const float* jang    = (const float*)d_in[1];
    const unsigned char* msk = (const unsigned char*)d_in[2];
    const int*   provide = (const int*)d_in[3];
    const float* conv_w  = (const float*)d_in[4];
    const float* conv_b  = (const float*)d_in[5];
    const float* w1      = (const float*)d_in[6];
    const float* b1      = (const float*)d_in[7];
    const float* w2      = (const float*)d_in[8];
    const float* b2      = (const float*)d_in[9];
    float* out = (float*)d_out;
    float* ws  = (float*)d_ws;

    float* CW    = ws + WS_CW;
    float* bX    = ws + WS_BX;
    float* X0    = ws + WS_X;
    float* preds = ws + WS_PR;
    float* Et    = ws + WS_ET;
    float* w2t   = ws + WS_W2T;
    // d_out scratch for K-split partials (rewritten by k_x every call,
    // consumed by k_sum, then overwritten by k_scan-copies/k_up)
    float* X1    = out;
    float* X2    = out + (size_t)MM * HD;
    float* X3    = out + (size_t)2 * MM * HD;

    hipLaunchKernelGGL(k_pre,  dim3(NB_E + NB_CW + 42), dim3(256), 0, stream,
                       emg, conv_w, w1, conv_b, b1, w2, Et, CW, bX, w2t);

    if (ws_size >= WS_NEED_BIG) {
        float* X4 = ws + WS_X4;
        float* X5 = ws + WS_X5;
        hipLaunchKernelGGL(k_x96, dim3(MM / 96, HD / 256, 6), dim3(192), 0, stream,
                           Et, CW, bX, X0, X1, X2, X3, X4, X5);
        hipLaunchKernelGGL(k_sum6, dim3(MM * HD / 4 / 256), dim3(256), 0, stream,
                           X0, X1, X2, X3, X4, X5);
    } else {
        hipLaunchKernelGGL(k_x12, dim3(MM / 64, HD / 256, 4), dim3(128), 0, stream,
                           Et, CW, bX, X0, X1, X2, X3);
        hipLaunchKernelGGL(k_sum4, dim3(MM * HD / 4 / 256), dim3(256), 0, stream,
                           X0, X1, X2, X3);
    }

    hipLaunchKernelGGL(k_scan, dim3(BB + 2 * BB * OUT + BB - BB * OUT), dim3(320), 0, stream,
                       X0, w1, w2t, b2, jang, provide, preds, msk, out);
    hipLaunchKernelGGL(k_up,   dim3(BB * OUT), dim3(256), 0, stream, preds, out);
}

// Round 17
// 252.839 us; speedup vs baseline: 1.0837x; 1.0837x over previous
//
#include <hip/hip_runtime.h>

#define NT   198     // n_time
#define BB   32      // batch
#define CC   16      // emg channels
#define TT   8000    // emg time
#define FF   512     // conv filters
#define KW   65      // conv kernel width
#define HD   512     // hidden
#define OUT  20
#define CJ   (CC*KW) // 1040
#define KP   1056    // K padded to 33*32
#define MM   (NT*BB) // 6336
#define TOUT 7936    // T - 64
#define NPS  50      // num_pos_steps

typedef float f4 __attribute__((ext_vector_type(4)));

// workspace layout (floats); base total = 10,623,232 floats = 42.5 MB
#define WS_CW 0                       // KP*HD = 540672
#define WS_BX (WS_CW + KP*HD)         // 540672
#define WS_X  (WS_BX + HD)            // 541184
#define WS_PR (WS_X  + MM*HD)         // 3785216
#define WS_ET (WS_PR + MM*OUT)        // 3911936
#define WS_W2T (WS_ET + KP*MM)        // 10602752

// direct global->LDS, 16B per lane (dest = wave-uniform base + lane*16)
__device__ __forceinline__ void gll16(const float* g, float* l) {
    __builtin_amdgcn_global_load_lds(
        (const __attribute__((address_space(1))) unsigned int*)g,
        (__attribute__((address_space(3))) unsigned int*)l,
        16, 0, 0);
}

// ---- k_pre: fused {Et interp+zero-pad | CW GEMM | bX + w2t} by block range ----
#define ESPAN 2688
#define NB_E  (3 * (BB * CC + 4))     // 1548
#define NB_CW (((KP + 63) / 64) * (HD / 64))  // 17*8 = 136
__global__ __launch_bounds__(256) void k_pre(const float* __restrict__ emg,
                                             const float* __restrict__ cwraw,
                                             const float* __restrict__ w1,
                                             const float* __restrict__ conv_b,
                                             const float* __restrict__ b1,
                                             const float* __restrict__ w2,
                                             float* __restrict__ Et,
                                             float* __restrict__ CW,
                                             float* __restrict__ bX,
                                             float* __restrict__ w2t) {
    __shared__ float sh[2 * 32 * 68];  // 4352 floats; aliased per role
    const int bid = blockIdx.x;
    const int tid = threadIdx.x;

    if (bid < NB_E) {
        // ---------- Et role ----------
        const int bx = bid % (BB * CC + 4);
        const int tc = bid / (BB * CC + 4);      // 0..2
        if (bx >= BB * CC) {                     // zero-pad rows CJ..KP-1
            int idx = (bx - BB * CC) * 3 + tc;   // 0..11
            f4* zp = (f4*)(Et + (size_t)CJ * MM);
            f4 z = {0.f, 0.f, 0.f, 0.f};
            for (int j = tid; j < 2112; j += 256) zp[(size_t)idx * 2112 + j] = z;
            return;
        }
        float* lds_e = sh;
        const int bq = bx >> 4, c = bx & 15;
        const int t0 = tc * 66;
        const float CSTEP = 7935.0f / 197.0f;
        const int elo0 = (int)floorf((float)t0 * CSTEP);
        const float* erow = emg + (size_t)(bq * CC + c) * TT;
        for (int i = tid; i < ESPAN; i += 256) {
            int g = elo0 + i;
            lds_e[i] = erow[(g < TT) ? g : (TT - 1)];
        }
        __syncthreads();
        for (int o = tid; o < 65 * 66; o += 256) {
            int j = o / 66;
            int tl = o - j * 66;
            int t = t0 + tl;
            float src = (float)t * CSTEP;
            float fl = floorf(src);
            int lo = (int)fl;
            float w = src - fl;
            int dhi = (w > 0.f && lo < TOUT - 1) ? 1 : 0;
            int li = lo - elo0 + j;
            float v = (1.0f - w) * lds_e[li] + w * lds_e[li + dhi];
            Et[(size_t)(c * KW + j) * MM + bq * NT + t] = v;
        }
    } else if (bid < NB_E + NB_CW) {
        // ---------- CW role: CW[cj][h] = sum_f conv_w[f][cj]*w1[f][h] ----------
        const int cb = bid - NB_E;
        const int m0 = (cb % 17) * 64;           // cj
        const int n0 = (cb / 17) * 64;           // h
        float (*As)[68] = (float(*)[68])sh;
        float (*Bs)[68] = (float(*)[68])(sh + 32 * 68);
        const int tx = tid & 15, ty = tid >> 4;
        const int am = tid & 63;
        const int kb8 = (tid >> 6) * 8;
        const int mrow = m0 + am;
        const int mclamp = mrow < CJ ? mrow : CJ - 1;

        f4 acc[4] = {};
        for (int k0 = 0; k0 < FF; k0 += 32) {
            __syncthreads();
            #pragma unroll
            for (int s = 0; s < 8; ++s)
                As[kb8 + s][am] = cwraw[(size_t)(k0 + kb8 + s) * CJ + mclamp];
            {
                int kb = tid >> 4, c4 = tid & 15;
                *(f4*)&Bs[kb][c4 * 4]      = *(const f4*)(w1 + (size_t)(k0 + kb) * HD + n0 + c4 * 4);
                *(f4*)&Bs[kb + 16][c4 * 4] = *(const f4*)(w1 + (size_t)(k0 + kb + 16) * HD + n0 + c4 * 4);
            }
            __syncthreads();
            #pragma unroll
            for (int kk = 0; kk < 32; ++kk) {
                f4 a = *(f4*)&As[kk][ty * 4];
                f4 bq = *(f4*)&Bs[kk][tx * 4];
                acc[0] += a[0] * bq; acc[1] += a[1] * bq;
                acc[2] += a[2] * bq; acc[3] += a[3] * bq;
            }
        }
        #pragma unroll
        for (int i = 0; i < 4; ++i) {
            int r = m0 + ty * 4 + i;
            if (r < CJ) {
                *(f4*)(CW + (size_t)r * HD + n0 + tx * 4) = acc[i];
            } else if (r < KP) {
                f4 z = {0.f, 0.f, 0.f, 0.f};
                *(f4*)(CW + (size_t)r * HD + n0 + tx * 4) = z;
            }
        }
    } else {
        // ---------- small role: bX (2 blocks) + w2t (40 blocks) ----------
        const int sb = bid - NB_E - NB_CW;       // 0..41
        if (sb < 2) {
            int h = sb * 256 + tid;
            float acc = b1[h];
            for (int f = 0; f < FF; ++f) acc += conv_b[f] * w1[f * HD + h];
            bX[h] = acc;
        } else {
            int q = sb - 2;                      // 0..39
            w2t[(size_t)q * HD + tid]       = w2[(size_t)tid * (2 * OUT) + q];
            w2t[(size_t)q * HD + 256 + tid] = w2[(size_t)(256 + tid) * (2 * OUT) + q];
        }
    }
}

// ---- k_x13: X = Et^T @ CW (+bX), tile 64x128, 128 thr, 8x8 micro, K-split 4,
//      staging via global_load_lds width-16 (no VGPR round-trip, no ds_writes) ----
__global__ __launch_bounds__(128) void k_x13(const float* __restrict__ Et,
                                             const float* __restrict__ CW,
                                             const float* __restrict__ bX,
                                             float* __restrict__ X0,
                                             float* __restrict__ X1,
                                             float* __restrict__ X2,
                                             float* __restrict__ X3) {
    __shared__ float As[32][64];     // contiguous (gll needs linear dest)
    __shared__ float Bs[32][128];
    const int m0 = blockIdx.x * 64;
    const int n0 = blockIdx.y * 128;
    const int kc = blockIdx.z;
    const int kbase = kc * 256;
    const int NK = (kc == 3) ? 9 : 8;    // rows >= CJ are zero-padded
    const int tid = threadIdx.x;
    const int tm = tid >> 4;             // 0..7 : rows 8tm..8tm+7
    const int tn = tid & 15;             // 0..15: cols tn*4 (lo) and 64+tn*4 (hi)
    const int wv = tid >> 6;             // wave id (uniform)
    const int lane = tid & 63;

    f4 acc0[8] = {}, acc1[8] = {};

    for (int kt = 0; kt < NK; ++kt) {
        const int k0 = kbase + kt * 32;
        __syncthreads();                 // previous compute done before overwrite
        // A: 8 wave-instrs total; wave wv issues ii = 4wv..4wv+3.
        // instr ii covers As rows 4ii..4ii+3 (1024B); lane l -> row 4ii+(l>>4),
        // col (l&15)*4.
        #pragma unroll
        for (int i = 0; i < 4; ++i) {
            int ii = wv * 4 + i;
            const float* src = Et + (size_t)(k0 + 4 * ii + (lane >> 4)) * MM
                             + m0 + (lane & 15) * 4;
            gll16(src, &As[4 * ii][0]);
        }
        // B: 16 wave-instrs total; wave wv issues jj = 8wv..8wv+7.
        // instr jj covers Bs rows 2jj..2jj+1 (1024B); lane l -> row 2jj+(l>>5),
        // col (l&31)*4.
        #pragma unroll
        for (int j = 0; j < 8; ++j) {
            int jj = wv * 8 + j;
            const float* src = CW + (size_t)(k0 + 2 * jj + (lane >> 5)) * HD
                             + n0 + (lane & 31) * 4;
            gll16(src, &Bs[2 * jj][0]);
        }
        __syncthreads();                 // drains vmcnt: all LDS writes landed
        #pragma unroll
        for (int kk = 0; kk < 32; ++kk) {
            f4 a0 = *(const f4*)&As[kk][tm * 8];
            f4 a1 = *(const f4*)&As[kk][tm * 8 + 4];
            f4 b0 = *(const f4*)&Bs[kk][tn * 4];
            f4 b1 = *(const f4*)&Bs[kk][64 + tn * 4];
            #pragma unroll
            for (int i = 0; i < 4; ++i) {
                acc0[i]     += a0[i] * b0;  acc1[i]     += a0[i] * b1;
                acc0[i + 4] += a1[i] * b0;  acc1[i + 4] += a1[i] * b1;
            }
        }
    }

    float* Xo = (kc == 0) ? X0 : (kc == 1) ? X1 : (kc == 2) ? X2 : X3;
    if (kc == 0) {
        f4 bx0 = *(const f4*)(bX + n0 + tn * 4);
        f4 bx1 = *(const f4*)(bX + n0 + 64 + tn * 4);
        #pragma unroll
        for (int i = 0; i < 8; ++i) {
            size_t off = (size_t)(m0 + 8 * tm + i) * HD + n0;
            *(f4*)(Xo + off + tn * 4)      = acc0[i] + bx0;
            *(f4*)(Xo + off + 64 + tn * 4) = acc1[i] + bx1;
        }
    } else {
        #pragma unroll
        for (int i = 0; i < 8; ++i) {
            size_t off = (size_t)(m0 + 8 * tm + i) * HD + n0;
            *(f4*)(Xo + off + tn * 4)      = acc0[i];
            *(f4*)(Xo + off + 64 + tn * 4) = acc1[i];
        }
    }
}

// ---- k_sum4: X0 += X1 + X2 + X3 ----
__global__ __launch_bounds__(256) void k_sum4(float* __restrict__ X0,
                                              const float* __restrict__ X1,
                                              const float* __restrict__ X2,
                                              const float* __restrict__ X3) {
    size_t i = (size_t)blockIdx.x * 256 + threadIdx.x;
    f4 a = ((const f4*)X0)[i];
    f4 b = ((const f4*)X1)[i];
    f4 c = ((const f4*)X2)[i];
    f4 d = ((const f4*)X3)[i];
    ((f4*)X0)[i] = (a + b) + (c + d);
}

// ---- scan (blocks 0..31) + ja/mask copies (blocks 32..703) ----
#define DPPADD(x, ctrl) ((x) + __int_as_float(__builtin_amdgcn_mov_dpp(__float_as_int(x), (ctrl), 0xf, 0xf, true)))

#define SCAN_STEP(T, ISPOS) { \
    if (aown) { \
        int tp = (T) + 2; if (tp > NT - 1) tp = NT - 1; \
        float2 xf = *(const float2*)(Xr + (size_t)tp * HD); \
        f4 pp[5]; \
        _Pragma("unroll") \
        for (int g = 0; g < 5; ++g) pp[g] = *(const f4*)&prev_lds[(T) & 1][g * 4]; \
        float h0a = xc.x, h0b = 0.f, h1a = xc.y, h1b = 0.f; \
        _Pragma("unroll") \
        for (int j = 0; j < 10; ++j) { \
            float pj = pp[j >> 2][j & 3]; \
            h0a = fmaf(pj, w1p[j].x, h0a); h1a = fmaf(pj, w1p[j].y, h1a); } \
        _Pragma("unroll") \
        for (int j = 10; j < OUT; ++j) { \
            float pj = pp[j >> 2][j & 3]; \
            h0b = fmaf(pj, w1p[j].x, h0b); h1b = fmaf(pj, w1p[j].y, h1b); } \
        float h0 = fmaxf(h0a + h0b, 0.f), h1 = fmaxf(h1a + h1b, 0.f); \
        float2 hw; hw.x = h0; hw.y = h1; \
        *(float2*)&h_lds[(T) & 1][tid >> 4][(2 * tid) & 31] = hw; \
        xc = xn; xn = xf; \
    } \
    __syncthreads(); \
    f4 alo = {0.f, 0.f, 0.f, 0.f}, ahi = {0.f, 0.f, 0.f, 0.f}; \
    _Pragma("unroll") \
    for (int s = 0; s < 4; ++s) { \
        f4 hv0 = *(const f4*)&h_lds[(T) & 1][r][s * 4]; \
        f4 hv1 = *(const f4*)&h_lds[(T) & 1][r][(s + 4) * 4]; \
        alo += hv0 * ((ISPOS) ? wqp[s] : wqv[s]); \
        ahi += hv1 * ((ISPOS) ? wqp[s + 4] : wqv[s + 4]); } \
    f4 a = alo + ahi; \
    float sum = (a[0] + a[1]) + (a[2] + a[3]); \
    sum = DPPADD(sum, 0xB1);   /* xor1  */ \
    sum = DPPADD(sum, 0x4E);   /* xor2  */ \
    sum = DPPADD(sum, 0x141);  /* row_half_mirror */ \
    sum = DPPADD(sum, 0x140);  /* row_mirror */ \
    float outv = sum + ((ISPOS) ? b2p : b2v); \
    myq = (ISPOS) ? outv : (myq + outv); \
    if (r == 0) { \
        predrow[(size_t)(T) * OUT + q] = myq; \
        prev_lds[((T) + 1) & 1][q] = myq; } \
    __syncthreads(); }

__global__ __launch_bounds__(320, 1) void k_scan(
        const float* __restrict__ X, const float* __restrict__ w1,
        const float* __restrict__ w2t, const float* __restrict__ b2,
        const float* __restrict__ jang, const int* __restrict__ provide,
        float* __restrict__ preds, const unsigned char* __restrict__ m,
        float* __restrict__ outp) {
    const int bid = blockIdx.x;
    const int tid = threadIdx.x;
    const int NF4 = TOUT / 4;    // 1984

    if (bid >= BB) {
        // ---- copy role: ja rows (cb<640) and mask rows (cb>=640) ----
        int cb = bid - BB;
        if (cb < BB * OUT) {
            f4* op = (f4*)(outp + (size_t)BB * OUT * TOUT + (size_t)cb * TOUT);
            const f4* ip = (const f4*)(jang + (size_t)cb * TT + 32);
            for (int i = tid; i < NF4; i += 320) op[i] = ip[i];
        } else {
            int b = cb - BB * OUT;
            f4* op = (f4*)(outp + (size_t)2 * BB * OUT * TOUT + (size_t)b * TOUT);
            const uchar4* mp = (const uchar4*)(m + (size_t)b * TT + 32);
            for (int i = tid; i < NF4; i += 320) {
                uchar4 mv = mp[i];
                f4 o;
                o[0] = mv.x ? 1.0f : 0.0f; o[1] = mv.y ? 1.0f : 0.0f;
                o[2] = mv.z ? 1.0f : 0.0f; o[3] = mv.w ? 1.0f : 0.0f;
                op[i] = o;
            }
        }
        return;
    }

    __shared__ float h_lds[2][16][36];
    __shared__ __align__(16) float prev_lds[2][20];
    const int b = bid;
    const int q = tid >> 4;        // 0..19
    const int r = tid & 15;        // 0..15
    const bool aown = tid < 256;

    float2 w1p[OUT];
    if (aown) {
        #pragma unroll
        for (int j = 0; j < OUT; ++j)
            w1p[j] = *(const float2*)(w1 + (size_t)(FF + j) * HD + 2 * tid);
    }
    f4 wqp[8], wqv[8];
    #pragma unroll
    for (int s = 0; s < 8; ++s) {
        wqp[s] = *(const f4*)(w2t + (size_t)q * HD + r * 32 + s * 4);
        wqv[s] = *(const f4*)(w2t + (size_t)(OUT + q) * HD + r * 32 + s * 4);
    }
    float b2p = b2[q], b2v = b2[OUT + q];

    float pvf = provide[0] ? 1.0f : 0.0f;
    float myq = pvf * jang[(size_t)(b * OUT + q) * TT + 32];
    if (r == 0) prev_lds[0][q] = myq;

    const float* Xr = X + (size_t)b * NT * HD + 2 * tid;
    float* predrow = preds + (size_t)b * NT * OUT;
    float2 xc = {0.f, 0.f}, xn = {0.f, 0.f};
    if (aown) {
        xc = *(const float2*)(Xr);
        xn = *(const float2*)(Xr + HD);
    }
    __syncthreads();

    for (int t = 0; t < NPS; ++t) { SCAN_STEP(t, true) }
    for (int t = NPS; t < NT; ++t) { SCAN_STEP(t, false) }
}

// ---- k_up: pred_up only (640 blocks), f4-vectorized ----
__global__ __launch_bounds__(256) void k_up(const float* __restrict__ preds,
                                            float* __restrict__ outp) {
    __shared__ float row[NT];
    const int rc = blockIdx.x;
    const int tid = threadIdx.x;
    const int NF4 = TOUT / 4;     // 1984
    int bq = rc / OUT, ch = rc - bq * OUT;
    if (tid < NT) row[tid] = preds[(size_t)(bq * NT + tid) * OUT + ch];
    __syncthreads();
    const float scale = (float)NT / (float)TOUT;
    f4* op = (f4*)(outp + (size_t)rc * TOUT);
    for (int i = tid; i < NF4; i += 256) {
        f4 o;
        #pragma unroll
        for (int e = 0; e < 4; ++e) {
            int idx = 4 * i + e;
            float src = ((float)idx + 0.5f) * scale - 0.5f;
            src = fminf(fmaxf(src, 0.0f), (float)(NT - 1));
            float fl = floorf(src);
            int lo = (int)fl;
            int hi = lo + 1; if (hi > NT - 1) hi = NT - 1;
            float w = src - fl;
            o[e] = row[lo] * (1.0f - w) + row[hi] * w;
        }
        op[i] = o;
    }
}

extern "C" void kernel_launch(void* const* d_in, const int* in_sizes, int n_in,
                              void* d_out, int out_size, void* d_ws, size_t ws_size,
                              hipStream_t stream) {
    const float* emg     = (const float*)d_in[0];
    const float* jang    = (const float*)d_in[1];
    const unsigned char* msk = (const unsigned char*)d_in[2];
    const int*   provide = (const int*)d_in[3];
    const float* conv_w  = (const float*)d_in[4];
    const float* conv_b  = (const float*)d_in[5];
    const float* w1      = (const float*)d_in[6];
    const float* b1      = (const float*)d_in[7];
    const float* w2      = (const float*)d_in[8];
    const float* b2      = (const float*)d_in[9];
    float* out = (float*)d_out;
    float* ws  = (float*)d_ws;

    float* CW    = ws + WS_CW;
    float* bX    = ws + WS_BX;
    float* X0    = ws + WS_X;
    float* preds = ws + WS_PR;
    float* Et    = ws + WS_ET;
    float* w2t   = ws + WS_W2T;
    // d_out scratch for K-split partials (rewritten by k_x13 every call,
    // consumed by k_sum4, then overwritten by k_scan-copies/k_up)
    float* X1    = out;
    float* X2    = out + (size_t)MM * HD;
    float* X3    = out + (size_t)2 * MM * HD;

    hipLaunchKernelGGL(k_pre,  dim3(NB_E + NB_CW + 42), dim3(256), 0, stream,
                       emg, conv_w, w1, conv_b, b1, w2, Et, CW, bX, w2t);
    hipLaunchKernelGGL(k_x13,  dim3(MM / 64, HD / 128, 4), dim3(128), 0, stream,
                       Et, CW, bX, X0, X1, X2, X3);
    hipLaunchKernelGGL(k_sum4, dim3(MM * HD / 4 / 256), dim3(256), 0, stream,
                       X0, X1, X2, X3);
    hipLaunchKernelGGL(k_scan, dim3(BB + 2 * BB * OUT + BB - BB * OUT), dim3(320), 0, stream,
                       X0, w1, w2t, b2, jang, provide, preds, msk, out);
    hipLaunchKernelGGL(k_up,   dim3(BB * OUT), dim3(256), 0, stream, preds, out);
}

// Round 18
// 251.291 us; speedup vs baseline: 1.0903x; 1.0062x over previous
//
#include <hip/hip_runtime.h>

#define NT   198     // n_time
#define BB   32      // batch
#define CC   16      // emg channels
#define TT   8000    // emg time
#define FF   512     // conv filters
#define KW   65      // conv kernel width
#define HD   512     // hidden
#define OUT  20
#define CJ   (CC*KW) // 1040
#define KP   1056    // K padded to 33*32
#define MM   (NT*BB) // 6336
#define TOUT 7936    // T - 64
#define NPS  50      // num_pos_steps

typedef float f4 __attribute__((ext_vector_type(4)));

// workspace layout (floats); base total = 10,623,232 floats = 42.5 MB
#define WS_CW 0                       // KP*HD = 540672
#define WS_BX (WS_CW + KP*HD)         // 540672
#define WS_X  (WS_BX + HD)            // 541184
#define WS_PR (WS_X  + MM*HD)         // 3785216
#define WS_ET (WS_PR + MM*OUT)        // 3911936
#define WS_W2T (WS_ET + KP*MM)        // 10602752

// direct global->LDS, 16B per lane (dest = wave-uniform base + lane*16)
__device__ __forceinline__ void gll16(const float* g, float* l) {
    __builtin_amdgcn_global_load_lds(
        (const __attribute__((address_space(1))) unsigned int*)g,
        (__attribute__((address_space(3))) unsigned int*)l,
        16, 0, 0);
}

// LDS-only barrier: orders ds ops across waves, leaves global loads in flight.
// (Used ONLY in k_scan, whose globals are wave-private; GEMMs keep __syncthreads.)
#define XBAR() do { asm volatile("s_waitcnt lgkmcnt(0)" ::: "memory"); \
                    __builtin_amdgcn_s_barrier(); } while (0)

// ---- k_pre: fused {Et interp+zero-pad | CW GEMM | bX + w2t} by block range ----
#define ESPAN 2688
#define NB_E  (3 * (BB * CC + 4))     // 1548
#define NB_CW (((KP + 63) / 64) * (HD / 64))  // 17*8 = 136
__global__ __launch_bounds__(256) void k_pre(const float* __restrict__ emg,
                                             const float* __restrict__ cwraw,
                                             const float* __restrict__ w1,
                                             const float* __restrict__ conv_b,
                                             const float* __restrict__ b1,
                                             const float* __restrict__ w2,
                                             float* __restrict__ Et,
                                             float* __restrict__ CW,
                                             float* __restrict__ bX,
                                             float* __restrict__ w2t) {
    __shared__ float sh[2 * 32 * 68];  // 4352 floats; aliased per role
    const int bid = blockIdx.x;
    const int tid = threadIdx.x;

    if (bid < NB_E) {
        // ---------- Et role ----------
        const int bx = bid % (BB * CC + 4);
        const int tc = bid / (BB * CC + 4);      // 0..2
        if (bx >= BB * CC) {                     // zero-pad rows CJ..KP-1
            int idx = (bx - BB * CC) * 3 + tc;   // 0..11
            f4* zp = (f4*)(Et + (size_t)CJ * MM);
            f4 z = {0.f, 0.f, 0.f, 0.f};
            for (int j = tid; j < 2112; j += 256) zp[(size_t)idx * 2112 + j] = z;
            return;
        }
        float* lds_e = sh;
        const int bq = bx >> 4, c = bx & 15;
        const int t0 = tc * 66;
        const float CSTEP = 7935.0f / 197.0f;
        const int elo0 = (int)floorf((float)t0 * CSTEP);
        const float* erow = emg + (size_t)(bq * CC + c) * TT;
        for (int i = tid; i < ESPAN; i += 256) {
            int g = elo0 + i;
            lds_e[i] = erow[(g < TT) ? g : (TT - 1)];
        }
        __syncthreads();
        for (int o = tid; o < 65 * 66; o += 256) {
            int j = o / 66;
            int tl = o - j * 66;
            int t = t0 + tl;
            float src = (float)t * CSTEP;
            float fl = floorf(src);
            int lo = (int)fl;
            float w = src - fl;
            int dhi = (w > 0.f && lo < TOUT - 1) ? 1 : 0;
            int li = lo - elo0 + j;
            float v = (1.0f - w) * lds_e[li] + w * lds_e[li + dhi];
            Et[(size_t)(c * KW + j) * MM + bq * NT + t] = v;
        }
    } else if (bid < NB_E + NB_CW) {
        // ---------- CW role: CW[cj][h] = sum_f conv_w[f][cj]*w1[f][h] ----------
        const int cb = bid - NB_E;
        const int m0 = (cb % 17) * 64;           // cj
        const int n0 = (cb / 17) * 64;           // h
        float (*As)[68] = (float(*)[68])sh;
        float (*Bs)[68] = (float(*)[68])(sh + 32 * 68);
        const int tx = tid & 15, ty = tid >> 4;
        const int am = tid & 63;
        const int kb8 = (tid >> 6) * 8;
        const int mrow = m0 + am;
        const int mclamp = mrow < CJ ? mrow : CJ - 1;

        f4 acc[4] = {};
        for (int k0 = 0; k0 < FF; k0 += 32) {
            __syncthreads();
            #pragma unroll
            for (int s = 0; s < 8; ++s)
                As[kb8 + s][am] = cwraw[(size_t)(k0 + kb8 + s) * CJ + mclamp];
            {
                int kb = tid >> 4, c4 = tid & 15;
                *(f4*)&Bs[kb][c4 * 4]      = *(const f4*)(w1 + (size_t)(k0 + kb) * HD + n0 + c4 * 4);
                *(f4*)&Bs[kb + 16][c4 * 4] = *(const f4*)(w1 + (size_t)(k0 + kb + 16) * HD + n0 + c4 * 4);
            }
            __syncthreads();
            #pragma unroll
            for (int kk = 0; kk < 32; ++kk) {
                f4 a = *(f4*)&As[kk][ty * 4];
                f4 bq = *(f4*)&Bs[kk][tx * 4];
                acc[0] += a[0] * bq; acc[1] += a[1] * bq;
                acc[2] += a[2] * bq; acc[3] += a[3] * bq;
            }
        }
        #pragma unroll
        for (int i = 0; i < 4; ++i) {
            int r = m0 + ty * 4 + i;
            if (r < CJ) {
                *(f4*)(CW + (size_t)r * HD + n0 + tx * 4) = acc[i];
            } else if (r < KP) {
                f4 z = {0.f, 0.f, 0.f, 0.f};
                *(f4*)(CW + (size_t)r * HD + n0 + tx * 4) = z;
            }
        }
    } else {
        // ---------- small role: bX (2 blocks) + w2t (40 blocks) ----------
        const int sb = bid - NB_E - NB_CW;       // 0..41
        if (sb < 2) {
            int h = sb * 256 + tid;
            float acc = b1[h];
            for (int f = 0; f < FF; ++f) acc += conv_b[f] * w1[f * HD + h];
            bX[h] = acc;
        } else {
            int q = sb - 2;                      // 0..39
            w2t[(size_t)q * HD + tid]       = w2[(size_t)tid * (2 * OUT) + q];
            w2t[(size_t)q * HD + 256 + tid] = w2[(size_t)(256 + tid) * (2 * OUT) + q];
        }
    }
}

// ---- k_x13: X = Et^T @ CW (+bX), tile 64x128, 128 thr, 8x8 micro, K-split 4,
//      staging via global_load_lds width-16 (no VGPR round-trip, no ds_writes) ----
__global__ __launch_bounds__(128) void k_x13(const float* __restrict__ Et,
                                             const float* __restrict__ CW,
                                             const float* __restrict__ bX,
                                             float* __restrict__ X0,
                                             float* __restrict__ X1,
                                             float* __restrict__ X2,
                                             float* __restrict__ X3) {
    __shared__ float As[32][64];     // contiguous (gll needs linear dest)
    __shared__ float Bs[32][128];
    const int m0 = blockIdx.x * 64;
    const int n0 = blockIdx.y * 128;
    const int kc = blockIdx.z;
    const int kbase = kc * 256;
    const int NK = (kc == 3) ? 9 : 8;    // rows >= CJ are zero-padded
    const int tid = threadIdx.x;
    const int tm = tid >> 4;             // 0..7 : rows 8tm..8tm+7
    const int tn = tid & 15;             // 0..15: cols tn*4 (lo) and 64+tn*4 (hi)
    const int wv = tid >> 6;             // wave id (uniform)
    const int lane = tid & 63;

    f4 acc0[8] = {}, acc1[8] = {};

    for (int kt = 0; kt < NK; ++kt) {
        const int k0 = kbase + kt * 32;
        __syncthreads();                 // previous compute done before overwrite
        #pragma unroll
        for (int i = 0; i < 4; ++i) {
            int ii = wv * 4 + i;
            const float* src = Et + (size_t)(k0 + 4 * ii + (lane >> 4)) * MM
                             + m0 + (lane & 15) * 4;
            gll16(src, &As[4 * ii][0]);
        }
        #pragma unroll
        for (int j = 0; j < 8; ++j) {
            int jj = wv * 8 + j;
            const float* src = CW + (size_t)(k0 + 2 * jj + (lane >> 5)) * HD
                             + n0 + (lane & 31) * 4;
            gll16(src, &Bs[2 * jj][0]);
        }
        __syncthreads();                 // drains vmcnt: all LDS writes landed
        #pragma unroll
        for (int kk = 0; kk < 32; ++kk) {
            f4 a0 = *(const f4*)&As[kk][tm * 8];
            f4 a1 = *(const f4*)&As[kk][tm * 8 + 4];
            f4 b0 = *(const f4*)&Bs[kk][tn * 4];
            f4 b1 = *(const f4*)&Bs[kk][64 + tn * 4];
            #pragma unroll
            for (int i = 0; i < 4; ++i) {
                acc0[i]     += a0[i] * b0;  acc1[i]     += a0[i] * b1;
                acc0[i + 4] += a1[i] * b0;  acc1[i + 4] += a1[i] * b1;
            }
        }
    }

    float* Xo = (kc == 0) ? X0 : (kc == 1) ? X1 : (kc == 2) ? X2 : X3;
    if (kc == 0) {
        f4 bx0 = *(const f4*)(bX + n0 + tn * 4);
        f4 bx1 = *(const f4*)(bX + n0 + 64 + tn * 4);
        #pragma unroll
        for (int i = 0; i < 8; ++i) {
            size_t off = (size_t)(m0 + 8 * tm + i) * HD + n0;
            *(f4*)(Xo + off + tn * 4)      = acc0[i] + bx0;
            *(f4*)(Xo + off + 64 + tn * 4) = acc1[i] + bx1;
        }
    } else {
        #pragma unroll
        for (int i = 0; i < 8; ++i) {
            size_t off = (size_t)(m0 + 8 * tm + i) * HD + n0;
            *(f4*)(Xo + off + tn * 4)      = acc0[i];
            *(f4*)(Xo + off + 64 + tn * 4) = acc1[i];
        }
    }
}

// ---- k_sum4: X0 += X1 + X2 + X3 ----
__global__ __launch_bounds__(256) void k_sum4(float* __restrict__ X0,
                                              const float* __restrict__ X1,
                                              const float* __restrict__ X2,
                                              const float* __restrict__ X3) {
    size_t i = (size_t)blockIdx.x * 256 + threadIdx.x;
    f4 a = ((const f4*)X0)[i];
    f4 b = ((const f4*)X1)[i];
    f4 c = ((const f4*)X2)[i];
    f4 d = ((const f4*)X3)[i];
    ((f4*)X0)[i] = (a + b) + (c + d);
}

// ---- scan (blocks 0..31) + ja/mask copies (blocks 32..703) ----
// Scan barriers are XBAR (LDS-order only): the t+2 X prefetch stays in flight
// across steps instead of being vmcnt-drained by __syncthreads every step.
#define DPPADD(x, ctrl) ((x) + __int_as_float(__builtin_amdgcn_mov_dpp(__float_as_int(x), (ctrl), 0xf, 0xf, true)))

#define SCAN_STEP(T, ISPOS) { \
    if (aown) { \
        int tp = (T) + 2; if (tp > NT - 1) tp = NT - 1; \
        float2 xf = *(const float2*)(Xr + (size_t)tp * HD); \
        f4 pp[5]; \
        _Pragma("unroll") \
        for (int g = 0; g < 5; ++g) pp[g] = *(const f4*)&prev_lds[(T) & 1][g * 4]; \
        float h0a = xc.x, h0b = 0.f, h1a = xc.y, h1b = 0.f; \
        _Pragma("unroll") \
        for (int j = 0; j < 10; ++j) { \
            float pj = pp[j >> 2][j & 3]; \
            h0a = fmaf(pj, w1p[j].x, h0a); h1a = fmaf(pj, w1p[j].y, h1a); } \
        _Pragma("unroll") \
        for (int j = 10; j < OUT; ++j) { \
            float pj = pp[j >> 2][j & 3]; \
            h0b = fmaf(pj, w1p[j].x, h0b); h1b = fmaf(pj, w1p[j].y, h1b); } \
        float h0 = fmaxf(h0a + h0b, 0.f), h1 = fmaxf(h1a + h1b, 0.f); \
        float2 hw; hw.x = h0; hw.y = h1; \
        *(float2*)&h_lds[(T) & 1][tid >> 4][(2 * tid) & 31] = hw; \
        xc = xn; xn = xf; \
    } \
    XBAR(); \
    f4 alo = {0.f, 0.f, 0.f, 0.f}, ahi = {0.f, 0.f, 0.f, 0.f}; \
    _Pragma("unroll") \
    for (int s = 0; s < 4; ++s) { \
        f4 hv0 = *(const f4*)&h_lds[(T) & 1][r][s * 4]; \
        f4 hv1 = *(const f4*)&h_lds[(T) & 1][r][(s + 4) * 4]; \
        alo += hv0 * ((ISPOS) ? wqp[s] : wqv[s]); \
        ahi += hv1 * ((ISPOS) ? wqp[s + 4] : wqv[s + 4]); } \
    f4 a = alo + ahi; \
    float sum = (a[0] + a[1]) + (a[2] + a[3]); \
    sum = DPPADD(sum, 0xB1);   /* xor1  */ \
    sum = DPPADD(sum, 0x4E);   /* xor2  */ \
    sum = DPPADD(sum, 0x141);  /* row_half_mirror */ \
    sum = DPPADD(sum, 0x140);  /* row_mirror */ \
    float outv = sum + ((ISPOS) ? b2p : b2v); \
    myq = (ISPOS) ? outv : (myq + outv); \
    if (r == 0) { \
        predrow[(size_t)(T) * OUT + q] = myq; \
        prev_lds[((T) + 1) & 1][q] = myq; } \
    XBAR(); }

__global__ __launch_bounds__(320, 1) void k_scan(
        const float* __restrict__ X, const float* __restrict__ w1,
        const float* __restrict__ w2t, const float* __restrict__ b2,
        const float* __restrict__ jang, const int* __restrict__ provide,
        float* __restrict__ preds, const unsigned char* __restrict__ m,
        float* __restrict__ outp) {
    const int bid = blockIdx.x;
    const int tid = threadIdx.x;
    const int NF4 = TOUT / 4;    // 1984

    if (bid >= BB) {
        // ---- copy role: ja rows (cb<640) and mask rows (cb>=640) ----
        int cb = bid - BB;
        if (cb < BB * OUT) {
            f4* op = (f4*)(outp + (size_t)BB * OUT * TOUT + (size_t)cb * TOUT);
            const f4* ip = (const f4*)(jang + (size_t)cb * TT + 32);
            for (int i = tid; i < NF4; i += 320) op[i] = ip[i];
        } else {
            int b = cb - BB * OUT;
            f4* op = (f4*)(outp + (size_t)2 * BB * OUT * TOUT + (size_t)b * TOUT);
            const uchar4* mp = (const uchar4*)(m + (size_t)b * TT + 32);
            for (int i = tid; i < NF4; i += 320) {
                uchar4 mv = mp[i];
                f4 o;
                o[0] = mv.x ? 1.0f : 0.0f; o[1] = mv.y ? 1.0f : 0.0f;
                o[2] = mv.z ? 1.0f : 0.0f; o[3] = mv.w ? 1.0f : 0.0f;
                op[i] = o;
            }
        }
        return;
    }

    __shared__ float h_lds[2][16][36];
    __shared__ __align__(16) float prev_lds[2][20];
    const int b = bid;
    const int q = tid >> 4;        // 0..19
    const int r = tid & 15;        // 0..15
    const bool aown = tid < 256;

    float2 w1p[OUT];
    if (aown) {
        #pragma unroll
        for (int j = 0; j < OUT; ++j)
            w1p[j] = *(const float2*)(w1 + (size_t)(FF + j) * HD + 2 * tid);
    }
    f4 wqp[8], wqv[8];
    #pragma unroll
    for (int s = 0; s < 8; ++s) {
        wqp[s] = *(const f4*)(w2t + (size_t)q * HD + r * 32 + s * 4);
        wqv[s] = *(const f4*)(w2t + (size_t)(OUT + q) * HD + r * 32 + s * 4);
    }
    float b2p = b2[q], b2v = b2[OUT + q];

    float pvf = provide[0] ? 1.0f : 0.0f;
    float myq = pvf * jang[(size_t)(b * OUT + q) * TT + 32];
    if (r == 0) prev_lds[0][q] = myq;

    const float* Xr = X + (size_t)b * NT * HD + 2 * tid;
    float* predrow = preds + (size_t)b * NT * OUT;
    float2 xc = {0.f, 0.f}, xn = {0.f, 0.f};
    if (aown) {
        xc = *(const float2*)(Xr);
        xn = *(const float2*)(Xr + HD);
    }
    XBAR();

    __builtin_amdgcn_s_setprio(1);
    for (int t = 0; t < NPS; ++t) { SCAN_STEP(t, true) }
    for (int t = NPS; t < NT; ++t) { SCAN_STEP(t, false) }
    __builtin_amdgcn_s_setprio(0);
}

// ---- k_up: pred_up only (640 blocks), f4-vectorized ----
__global__ __launch_bounds__(256) void k_up(const float* __restrict__ preds,
                                            float* __restrict__ outp) {
    __shared__ float row[NT];
    const int rc = blockIdx.x;
    const int tid = threadIdx.x;
    const int NF4 = TOUT / 4;     // 1984
    int bq = rc / OUT, ch = rc - bq * OUT;
    if (tid < NT) row[tid] = preds[(size_t)(bq * NT + tid) * OUT + ch];
    __syncthreads();
    const float scale = (float)NT / (float)TOUT;
    f4* op = (f4*)(outp + (size_t)rc * TOUT);
    for (int i = tid; i < NF4; i += 256) {
        f4 o;
        #pragma unroll
        for (int e = 0; e < 4; ++e) {
            int idx = 4 * i + e;
            float src = ((float)idx + 0.5f) * scale - 0.5f;
            src = fminf(fmaxf(src, 0.0f), (float)(NT - 1));
            float fl = floorf(src);
            int lo = (int)fl;
            int hi = lo + 1; if (hi > NT - 1) hi = NT - 1;
            float w = src - fl;
            o[e] = row[lo] * (1.0f - w) + row[hi] * w;
        }
        op[i] = o;
    }
}

extern "C" void kernel_launch(void* const* d_in, const int* in_sizes, int n_in,
                              void* d_out, int out_size, void* d_ws, size_t ws_size,
                              hipStream_t stream) {
    const float* emg     = (const float*)d_in[0];
    const float* jang    = (const float*)d_in[1];
    const unsigned char* msk = (const unsigned char*)d_in[2];
    const int*   provide = (const int*)d_in[3];
    const float* conv_w  = (const float*)d_in[4];
    const float* conv_b  = (const float*)d_in[5];
    const float* w1      = (const float*)d_in[6];
    const float* b1      = (const float*)d_in[7];
    const float* w2      = (const float*)d_in[8];
    const float* b2      = (const float*)d_in[9];
    float* out = (float*)d_out;
    float* ws  = (float*)d_ws;

    float* CW    = ws + WS_CW;
    float* bX    = ws + WS_BX;
    float* X0    = ws + WS_X;
    float* preds = ws + WS_PR;
    float* Et    = ws + WS_ET;
    float* w2t   = ws + WS_W2T;
    // d_out scratch for K-split partials (rewritten by k_x13 every call,
    // consumed by k_sum4, then overwritten by k_scan-copies/k_up)
    float* X1    = out;
    float* X2    = out + (size_t)MM * HD;
    float* X3    = out + (size_t)2 * MM * HD;

    hipLaunchKernelGGL(k_pre,  dim3(NB_E + NB_CW + 42), dim3(256), 0, stream,
                       emg, conv_w, w1, conv_b, b1, w2, Et, CW, bX, w2t);
    hipLaunchKernelGGL(k_x13,  dim3(MM / 64, HD / 128, 4), dim3(128), 0, stream,
                       Et, CW, bX, X0, X1, X2, X3);
    hipLaunchKernelGGL(k_sum4, dim3(MM * HD / 4 / 256), dim3(256), 0, stream,
                       X0, X1, X2, X3);
    hipLaunchKernelGGL(k_scan, dim3(BB + 2 * BB * OUT + BB - BB * OUT), dim3(320), 0, stream,
                       X0, w1, w2t, b2, jang, provide, preds, msk, out);
    hipLaunchKernelGGL(k_up,   dim3(BB * OUT), dim3(256), 0, stream, preds, out);
}